// Round 3
// baseline (27070.300 us; speedup 1.0000x reference)
//
#include <hip/hip_runtime.h>

// Message passing GNN: 5 rounds of {segment_sum x2, node MLP 48->64->16, edge MLP 48->64->16}
// N=100000 nodes, E=3200000 edges, F=16 features.
//
// Layouts:
//   edges: [F, E] feature-major (matches reference, coalesced across lanes)
//   nodes output: [F, N] (matches reference)
//   nodes_t / sent / recv: [N, 16] node-major (gathers & atomics hit one 64B line per node)
//
// Round r+1's segment-sum is fused into round r's edge-MLP epilogue (atomicAdd of the
// freshly computed edge features), so edges are read from HBM once per round.

#define BLK 256

__device__ __forceinline__ void mlp48(const float* __restrict__ W1,
                                      const float* __restrict__ b1,
                                      const float* __restrict__ W2,
                                      const float* __restrict__ b2,
                                      const float* __restrict__ x,  // [48]
                                      float* __restrict__ out)      // [16]
{
#pragma unroll
    for (int o = 0; o < 16; ++o) out[o] = b2[o];
#pragma unroll 4
    for (int h = 0; h < 64; ++h) {
        float acc = b1[h];
#pragma unroll
        for (int f = 0; f < 48; ++f) acc = fmaf(W1[h * 48 + f], x[f], acc);
        acc = fmaxf(acc, 0.0f);
#pragma unroll
        for (int o = 0; o < 16; ++o) out[o] = fmaf(W2[o * 64 + h], acc, out[o]);
    }
}

// Round-1 scatter: segment-sum input edges into sent/recv accumulators ([N,16] layout).
__global__ void scatter_kernel(const float* __restrict__ edges,  // [F,E]
                               const int* __restrict__ senders,
                               const int* __restrict__ receivers,
                               float* __restrict__ sent,   // [N,16]
                               float* __restrict__ recv,   // [N,16]
                               int E_)
{
    int e = blockIdx.x * BLK + threadIdx.x;
    if (e >= E_) return;
    int s = senders[e];
    int r = receivers[e];
#pragma unroll
    for (int f = 0; f < 16; ++f) {
        float v = edges[(size_t)f * E_ + e];
        atomicAdd(sent + (size_t)s * 16 + f, v);
        atomicAdd(recv + (size_t)r * 16 + f, v);
    }
}

__global__ void node_mlp_kernel(const float* __restrict__ nodes_in,  // [F,N]
                                const float* __restrict__ sent,      // [N,16]
                                const float* __restrict__ recv,      // [N,16]
                                const float* __restrict__ W1,
                                const float* __restrict__ b1,
                                const float* __restrict__ W2,
                                const float* __restrict__ b2,
                                float* __restrict__ nodes_out,  // [F,N]
                                float* __restrict__ nodes_t,    // [N,16]
                                int N_)
{
    int n = blockIdx.x * BLK + threadIdx.x;
    if (n >= N_) return;
    float x[48];
#pragma unroll
    for (int f = 0; f < 16; ++f) x[f] = nodes_in[(size_t)f * N_ + n];
    const float4* sp = (const float4*)(sent + (size_t)n * 16);
    const float4* rp = (const float4*)(recv + (size_t)n * 16);
#pragma unroll
    for (int q = 0; q < 4; ++q) {
        float4 v = sp[q];
        x[16 + 4 * q + 0] = v.x; x[16 + 4 * q + 1] = v.y;
        x[16 + 4 * q + 2] = v.z; x[16 + 4 * q + 3] = v.w;
    }
#pragma unroll
    for (int q = 0; q < 4; ++q) {
        float4 v = rp[q];
        x[32 + 4 * q + 0] = v.x; x[32 + 4 * q + 1] = v.y;
        x[32 + 4 * q + 2] = v.z; x[32 + 4 * q + 3] = v.w;
    }
    float out[16];
    mlp48(W1, b1, W2, b2, x, out);
#pragma unroll
    for (int f = 0; f < 16; ++f) nodes_out[(size_t)f * N_ + n] = out[f];
    float4* tp = (float4*)(nodes_t + (size_t)n * 16);
#pragma unroll
    for (int q = 0; q < 4; ++q)
        tp[q] = make_float4(out[4 * q + 0], out[4 * q + 1], out[4 * q + 2], out[4 * q + 3]);
}

template <int DO_SCATTER>
__global__ void edge_mlp_kernel(const float* __restrict__ edges_in,  // [F,E]
                                const float* __restrict__ nodes_t,   // [N,16]
                                const int* __restrict__ senders,
                                const int* __restrict__ receivers,
                                const float* __restrict__ W1,
                                const float* __restrict__ b1,
                                const float* __restrict__ W2,
                                const float* __restrict__ b2,
                                float* __restrict__ edges_out,  // [F,E]
                                float* __restrict__ sentb,      // [N,16] next-round accum
                                float* __restrict__ recvb,      // [N,16]
                                int E_)
{
    int e = blockIdx.x * BLK + threadIdx.x;
    if (e >= E_) return;
    int s = senders[e];
    int r = receivers[e];
    float x[48];
#pragma unroll
    for (int f = 0; f < 16; ++f) x[f] = edges_in[(size_t)f * E_ + e];
    const float4* sp = (const float4*)(nodes_t + (size_t)s * 16);
    const float4* rp = (const float4*)(nodes_t + (size_t)r * 16);
#pragma unroll
    for (int q = 0; q < 4; ++q) {
        float4 v = sp[q];
        x[16 + 4 * q + 0] = v.x; x[16 + 4 * q + 1] = v.y;
        x[16 + 4 * q + 2] = v.z; x[16 + 4 * q + 3] = v.w;
    }
#pragma unroll
    for (int q = 0; q < 4; ++q) {
        float4 v = rp[q];
        x[32 + 4 * q + 0] = v.x; x[32 + 4 * q + 1] = v.y;
        x[32 + 4 * q + 2] = v.z; x[32 + 4 * q + 3] = v.w;
    }
    float out[16];
    mlp48(W1, b1, W2, b2, x, out);
#pragma unroll
    for (int f = 0; f < 16; ++f) edges_out[(size_t)f * E_ + e] = out[f];
    if (DO_SCATTER) {
#pragma unroll
        for (int f = 0; f < 16; ++f) {
            atomicAdd(sentb + (size_t)s * 16 + f, out[f]);
            atomicAdd(recvb + (size_t)r * 16 + f, out[f]);
        }
    }
}

extern "C" void kernel_launch(void* const* d_in, const int* in_sizes, int n_in,
                              void* d_out, int out_size, void* d_ws, size_t ws_size,
                              hipStream_t stream)
{
    const float* nodes0 = (const float*)d_in[0];
    const float* edges0 = (const float*)d_in[1];
    const int* receivers = (const int*)d_in[2];
    const int* senders = (const int*)d_in[3];
    const float* nW1 = (const float*)d_in[4];
    const float* nb1 = (const float*)d_in[5];
    const float* nW2 = (const float*)d_in[6];
    const float* nb2 = (const float*)d_in[7];
    const float* eW1 = (const float*)d_in[8];
    const float* eb1 = (const float*)d_in[9];
    const float* eW2 = (const float*)d_in[10];
    const float* eb2 = (const float*)d_in[11];

    const int N_ = in_sizes[0] / 16;  // 100000
    const int E_ = in_sizes[2];       // 3200000

    float* out_nodes = (float*)d_out;                       // [F,N]
    float* out_edges = out_nodes + (size_t)16 * N_;         // [F,E]

    float* wsf = (float*)d_ws;
    float* SR0 = wsf;                                // S0 then R0, each [N,16]
    float* S0 = SR0;
    float* R0 = SR0 + (size_t)16 * N_;
    float* SR1 = wsf + (size_t)32 * N_;
    float* S1 = SR1;
    float* R1 = SR1 + (size_t)16 * N_;
    float* nodes_t = wsf + (size_t)64 * N_;          // [N,16]

    const int gridE = (E_ + BLK - 1) / BLK;
    const int gridN = (N_ + BLK - 1) / BLK;

    // Round-1 segment sums from the input edges.
    hipMemsetAsync(SR0, 0, sizeof(float) * (size_t)32 * N_, stream);
    scatter_kernel<<<gridE, BLK, 0, stream>>>(edges0, senders, receivers, S0, R0, E_);

    const float* ncur = nodes0;
    const float* ecur = edges0;
    for (int r = 0; r < 5; ++r) {
        float* Scur = (r & 1) ? S1 : S0;
        float* Rcur = (r & 1) ? R1 : R0;
        float* Snxt = (r & 1) ? S0 : S1;
        float* Rnxt = (r & 1) ? R0 : R1;

        node_mlp_kernel<<<gridN, BLK, 0, stream>>>(ncur, Scur, Rcur,
                                                   nW1, nb1, nW2, nb2,
                                                   out_nodes, nodes_t, N_);
        if (r < 4) {
            hipMemsetAsync((r & 1) ? SR0 : SR1, 0, sizeof(float) * (size_t)32 * N_, stream);
            edge_mlp_kernel<1><<<gridE, BLK, 0, stream>>>(ecur, nodes_t, senders, receivers,
                                                          eW1, eb1, eW2, eb2,
                                                          out_edges, Snxt, Rnxt, E_);
        } else {
            edge_mlp_kernel<0><<<gridE, BLK, 0, stream>>>(ecur, nodes_t, senders, receivers,
                                                          eW1, eb1, eW2, eb2,
                                                          out_edges, nullptr, nullptr, E_);
        }
        ncur = out_nodes;
        ecur = out_edges;
    }
}

// Round 4
// 4554.540 us; speedup vs baseline: 5.9436x; 5.9436x over previous
//
#include <hip/hip_runtime.h>

// Message passing GNN: 5 rounds of {segment_sum x2, node MLP 48->64->16, edge MLP 48->64->16}
// N=100000 nodes, E=3200000 edges, F=16.
//
// Round-3 lesson: 32 fp32 atomicAdds/edge = 102M device-scope RMWs = 3.4GB WRITE_SIZE,
// atomic-throughput-bound at 19G/s. This version has ZERO float atomics:
//   - CSR build per launch (int histogram + scan + fill; 12.8M int atomics total)
//   - segment sums as gathers: 16 lanes per node stream its edge rows and sum in registers
//   - edges held as [E,16] bf16 rows between rounds (in-place update); final round writes
//     [F,E] fp32 to d_out directly.
// Fallback to the (passing, slow) atomic path if ws_size is too small for CSR+rows.

#define BLK 256

// ---------------- bf16 helpers (manual, ushort-based) ----------------
__device__ __forceinline__ float bf_lo(unsigned u) { return __uint_as_float(u << 16); }
__device__ __forceinline__ float bf_hi(unsigned u) { return __uint_as_float(u & 0xffff0000u); }
__device__ __forceinline__ float bf1(unsigned short u) { return __uint_as_float(((unsigned)u) << 16); }
__device__ __forceinline__ unsigned short f2bf(float f) {
    unsigned u = __float_as_uint(f);
    u = u + 0x7fffu + ((u >> 16) & 1u);  // RNE
    return (unsigned short)(u >> 16);
}
__device__ __forceinline__ unsigned pk2(float a, float b) {
    return (unsigned)f2bf(a) | ((unsigned)f2bf(b) << 16);
}

// ---------------- shared MLP ----------------
__device__ __forceinline__ void mlp48(const float* __restrict__ W1,
                                      const float* __restrict__ b1,
                                      const float* __restrict__ W2,
                                      const float* __restrict__ b2,
                                      const float* __restrict__ x,  // [48]
                                      float* __restrict__ out)      // [16]
{
#pragma unroll
    for (int o = 0; o < 16; ++o) out[o] = b2[o];
#pragma unroll 4
    for (int h = 0; h < 64; ++h) {
        float acc = b1[h];
#pragma unroll
        for (int f = 0; f < 48; ++f) acc = fmaf(W1[h * 48 + f], x[f], acc);
        acc = fmaxf(acc, 0.0f);
#pragma unroll
        for (int o = 0; o < 16; ++o) out[o] = fmaf(W2[o * 64 + h], acc, out[o]);
    }
}

// ---------------- CSR build ----------------
__global__ void hist_kernel(const int* __restrict__ s, const int* __restrict__ r,
                            int* __restrict__ deg_s, int* __restrict__ deg_r, int E_)
{
    int e = blockIdx.x * BLK + threadIdx.x;
    if (e >= E_) return;
    atomicAdd(deg_s + s[e], 1);
    atomicAdd(deg_r + r[e], 1);
}

// 256 threads, 1024 elements per block: local exclusive scan + block sums
__global__ void scan_local_kernel(const int* __restrict__ in, int* __restrict__ out,
                                  int* __restrict__ bsums, int n)
{
    __shared__ int lds[256];
    int t = threadIdx.x;
    int base = blockIdx.x * 1024;
    int v[4];
    int s = 0;
#pragma unroll
    for (int k = 0; k < 4; ++k) {
        int i = base + t * 4 + k;
        v[k] = (i < n) ? in[i] : 0;
        s += v[k];
    }
    lds[t] = s;
    __syncthreads();
    for (int d = 1; d < 256; d <<= 1) {
        int x = 0;
        if (t >= d) x = lds[t - d];
        __syncthreads();
        if (t >= d) lds[t] += x;
        __syncthreads();
    }
    int excl = (t > 0) ? lds[t - 1] : 0;
#pragma unroll
    for (int k = 0; k < 4; ++k) {
        int i = base + t * 4 + k;
        if (i < n) out[i] = excl;
        excl += v[k];
    }
    if (t == 255) bsums[blockIdx.x] = lds[255];
}

// single block: exclusive scan of block sums in place (nb <= 256)
__global__ void scan_tops_kernel(int* __restrict__ bsums, int nb)
{
    __shared__ int lds[256];
    int t = threadIdx.x;
    int v = (t < nb) ? bsums[t] : 0;
    lds[t] = v;
    __syncthreads();
    for (int d = 1; d < 256; d <<= 1) {
        int x = 0;
        if (t >= d) x = lds[t - d];
        __syncthreads();
        if (t >= d) lds[t] += x;
        __syncthreads();
    }
    int excl = (t > 0) ? lds[t - 1] : 0;
    if (t < nb) bsums[t] = excl;
}

__global__ void scan_add_kernel(int* __restrict__ off, const int* __restrict__ bsums,
                                int n, int total)
{
    int base = blockIdx.x * 1024;
    int add = bsums[blockIdx.x];
#pragma unroll
    for (int k = 0; k < 4; ++k) {
        int i = base + threadIdx.x * 4 + k;
        if (i < n) off[i] += add;
    }
    if (blockIdx.x == 0 && threadIdx.x == 0) off[n] = total;
}

__global__ void copy2_kernel(const int* __restrict__ a, int* __restrict__ b,
                             const int* __restrict__ c, int* __restrict__ d, int n)
{
    int i = blockIdx.x * BLK + threadIdx.x;
    if (i >= n) return;
    b[i] = a[i];
    d[i] = c[i];
}

__global__ void fill_kernel(const int* __restrict__ s, const int* __restrict__ r,
                            int* __restrict__ cur_s, int* __restrict__ cur_r,
                            int* __restrict__ eids_s, int* __restrict__ eids_r, int E_)
{
    int e = blockIdx.x * BLK + threadIdx.x;
    if (e >= E_) return;
    int is = atomicAdd(cur_s + s[e], 1);
    eids_s[is] = e;
    int ir = atomicAdd(cur_r + r[e], 1);
    eids_r[ir] = e;
}

// ---------------- data movement ----------------
// edges0 [F,E] fp32 -> rows [E,16] bf16
__global__ void transpose_in_kernel(const float* __restrict__ edges0,
                                    unsigned short* __restrict__ rows, int E_)
{
    int e = blockIdx.x * BLK + threadIdx.x;
    if (e >= E_) return;
    float v[16];
#pragma unroll
    for (int f = 0; f < 16; ++f) v[f] = edges0[(size_t)f * E_ + e];
    uint4 a, b;
    a.x = pk2(v[0], v[1]);  a.y = pk2(v[2], v[3]);
    a.z = pk2(v[4], v[5]);  a.w = pk2(v[6], v[7]);
    b.x = pk2(v[8], v[9]);  b.y = pk2(v[10], v[11]);
    b.z = pk2(v[12], v[13]); b.w = pk2(v[14], v[15]);
    uint4* wp = (uint4*)(rows + (size_t)e * 16);
    wp[0] = a;
    wp[1] = b;
}

// gather-based segment sum: 16 lanes per node, lane = feature
__global__ void aggregate_kernel(const unsigned short* __restrict__ rows,
                                 const int* __restrict__ off, const int* __restrict__ eids,
                                 float* __restrict__ out, int N_)
{
    int t = blockIdx.x * BLK + threadIdx.x;
    int g = t >> 4;
    int f = t & 15;
    if (g >= N_) return;
    int a = off[g], b = off[g + 1];
    float acc = 0.0f;
    for (int i = a; i < b; ++i) {
        int e = eids[i];
        acc += bf1(rows[(size_t)e * 16 + f]);
    }
    out[(size_t)g * 16 + f] = acc;
}

// ---------------- MLP kernels ----------------
__global__ void node_mlp_kernel(const float* __restrict__ nodes_in,  // [F,N]
                                const float* __restrict__ sent,      // [N,16]
                                const float* __restrict__ recv,      // [N,16]
                                const float* __restrict__ W1,
                                const float* __restrict__ b1,
                                const float* __restrict__ W2,
                                const float* __restrict__ b2,
                                float* __restrict__ nodes_out,  // [F,N]
                                float* __restrict__ nodes_t,    // [N,16]
                                int N_)
{
    int n = blockIdx.x * BLK + threadIdx.x;
    if (n >= N_) return;
    float x[48];
#pragma unroll
    for (int f = 0; f < 16; ++f) x[f] = nodes_in[(size_t)f * N_ + n];
    const float4* sp = (const float4*)(sent + (size_t)n * 16);
    const float4* rp = (const float4*)(recv + (size_t)n * 16);
#pragma unroll
    for (int q = 0; q < 4; ++q) {
        float4 v = sp[q];
        x[16 + 4 * q + 0] = v.x; x[16 + 4 * q + 1] = v.y;
        x[16 + 4 * q + 2] = v.z; x[16 + 4 * q + 3] = v.w;
    }
#pragma unroll
    for (int q = 0; q < 4; ++q) {
        float4 v = rp[q];
        x[32 + 4 * q + 0] = v.x; x[32 + 4 * q + 1] = v.y;
        x[32 + 4 * q + 2] = v.z; x[32 + 4 * q + 3] = v.w;
    }
    float out[16];
    mlp48(W1, b1, W2, b2, x, out);
#pragma unroll
    for (int f = 0; f < 16; ++f) nodes_out[(size_t)f * N_ + n] = out[f];
    float4* tp = (float4*)(nodes_t + (size_t)n * 16);
#pragma unroll
    for (int q = 0; q < 4; ++q)
        tp[q] = make_float4(out[4 * q + 0], out[4 * q + 1], out[4 * q + 2], out[4 * q + 3]);
}

// edge MLP over [E,16] bf16 rows, in-place; LAST round writes [F,E] fp32 instead.
template <int LAST>
__global__ void edge_mlp_rows_kernel(unsigned short* __restrict__ rows,  // [E,16] bf16
                                     const float* __restrict__ nodes_t,  // [N,16]
                                     const int* __restrict__ senders,
                                     const int* __restrict__ receivers,
                                     const float* __restrict__ W1,
                                     const float* __restrict__ b1,
                                     const float* __restrict__ W2,
                                     const float* __restrict__ b2,
                                     float* __restrict__ out_fe,  // [F,E] (LAST only)
                                     int E_)
{
    int e = blockIdx.x * BLK + threadIdx.x;
    if (e >= E_) return;
    const uint4* rp4 = (const uint4*)(rows + (size_t)e * 16);
    uint4 A = rp4[0], B = rp4[1];
    float x[48];
    x[0] = bf_lo(A.x); x[1] = bf_hi(A.x); x[2] = bf_lo(A.y); x[3] = bf_hi(A.y);
    x[4] = bf_lo(A.z); x[5] = bf_hi(A.z); x[6] = bf_lo(A.w); x[7] = bf_hi(A.w);
    x[8] = bf_lo(B.x); x[9] = bf_hi(B.x); x[10] = bf_lo(B.y); x[11] = bf_hi(B.y);
    x[12] = bf_lo(B.z); x[13] = bf_hi(B.z); x[14] = bf_lo(B.w); x[15] = bf_hi(B.w);
    int s = senders[e];
    int r = receivers[e];
    const float4* sp = (const float4*)(nodes_t + (size_t)s * 16);
    const float4* rp = (const float4*)(nodes_t + (size_t)r * 16);
#pragma unroll
    for (int q = 0; q < 4; ++q) {
        float4 v = sp[q];
        x[16 + 4 * q + 0] = v.x; x[16 + 4 * q + 1] = v.y;
        x[16 + 4 * q + 2] = v.z; x[16 + 4 * q + 3] = v.w;
    }
#pragma unroll
    for (int q = 0; q < 4; ++q) {
        float4 v = rp[q];
        x[32 + 4 * q + 0] = v.x; x[32 + 4 * q + 1] = v.y;
        x[32 + 4 * q + 2] = v.z; x[32 + 4 * q + 3] = v.w;
    }
    float out[16];
    mlp48(W1, b1, W2, b2, x, out);
    if (LAST) {
#pragma unroll
        for (int f = 0; f < 16; ++f) out_fe[(size_t)f * E_ + e] = out[f];
    } else {
        uint4 wa, wb;
        wa.x = pk2(out[0], out[1]);  wa.y = pk2(out[2], out[3]);
        wa.z = pk2(out[4], out[5]);  wa.w = pk2(out[6], out[7]);
        wb.x = pk2(out[8], out[9]);  wb.y = pk2(out[10], out[11]);
        wb.z = pk2(out[12], out[13]); wb.w = pk2(out[14], out[15]);
        uint4* wp = (uint4*)(rows + (size_t)e * 16);
        wp[0] = wa;
        wp[1] = wb;
    }
}

// ---------------- fallback (atomic) path kernels ----------------
__global__ void scatter_kernel(const float* __restrict__ edges,
                               const int* __restrict__ senders,
                               const int* __restrict__ receivers,
                               float* __restrict__ sent, float* __restrict__ recv, int E_)
{
    int e = blockIdx.x * BLK + threadIdx.x;
    if (e >= E_) return;
    int s = senders[e];
    int r = receivers[e];
#pragma unroll
    for (int f = 0; f < 16; ++f) {
        float v = edges[(size_t)f * E_ + e];
        atomicAdd(sent + (size_t)s * 16 + f, v);
        atomicAdd(recv + (size_t)r * 16 + f, v);
    }
}

template <int DO_SCATTER>
__global__ void edge_mlp_kernel(const float* __restrict__ edges_in,
                                const float* __restrict__ nodes_t,
                                const int* __restrict__ senders,
                                const int* __restrict__ receivers,
                                const float* __restrict__ W1, const float* __restrict__ b1,
                                const float* __restrict__ W2, const float* __restrict__ b2,
                                float* __restrict__ edges_out,
                                float* __restrict__ sentb, float* __restrict__ recvb, int E_)
{
    int e = blockIdx.x * BLK + threadIdx.x;
    if (e >= E_) return;
    int s = senders[e];
    int r = receivers[e];
    float x[48];
#pragma unroll
    for (int f = 0; f < 16; ++f) x[f] = edges_in[(size_t)f * E_ + e];
    const float4* sp = (const float4*)(nodes_t + (size_t)s * 16);
    const float4* rp = (const float4*)(nodes_t + (size_t)r * 16);
#pragma unroll
    for (int q = 0; q < 4; ++q) {
        float4 v = sp[q];
        x[16 + 4 * q + 0] = v.x; x[16 + 4 * q + 1] = v.y;
        x[16 + 4 * q + 2] = v.z; x[16 + 4 * q + 3] = v.w;
    }
#pragma unroll
    for (int q = 0; q < 4; ++q) {
        float4 v = rp[q];
        x[32 + 4 * q + 0] = v.x; x[32 + 4 * q + 1] = v.y;
        x[32 + 4 * q + 2] = v.z; x[32 + 4 * q + 3] = v.w;
    }
    float out[16];
    mlp48(W1, b1, W2, b2, x, out);
#pragma unroll
    for (int f = 0; f < 16; ++f) edges_out[(size_t)f * E_ + e] = out[f];
    if (DO_SCATTER) {
#pragma unroll
        for (int f = 0; f < 16; ++f) {
            atomicAdd(sentb + (size_t)s * 16 + f, out[f]);
            atomicAdd(recvb + (size_t)r * 16 + f, out[f]);
        }
    }
}

// ---------------- launch ----------------
extern "C" void kernel_launch(void* const* d_in, const int* in_sizes, int n_in,
                              void* d_out, int out_size, void* d_ws, size_t ws_size,
                              hipStream_t stream)
{
    const float* nodes0 = (const float*)d_in[0];
    const float* edges0 = (const float*)d_in[1];
    const int* receivers = (const int*)d_in[2];
    const int* senders = (const int*)d_in[3];
    const float* nW1 = (const float*)d_in[4];
    const float* nb1 = (const float*)d_in[5];
    const float* nW2 = (const float*)d_in[6];
    const float* nb2 = (const float*)d_in[7];
    const float* eW1 = (const float*)d_in[8];
    const float* eb1 = (const float*)d_in[9];
    const float* eW2 = (const float*)d_in[10];
    const float* eb2 = (const float*)d_in[11];

    const int N_ = in_sizes[0] / 16;  // 100000
    const int E_ = in_sizes[2];       // 3200000

    float* out_nodes = (float*)d_out;                // [F,N]
    float* out_edges = out_nodes + (size_t)16 * N_;  // [F,E]

    const int gridE = (E_ + BLK - 1) / BLK;
    const int gridN = (N_ + BLK - 1) / BLK;

    // ---- workspace carve for CSR path ----
    auto al = [](size_t x) { return (x + 255) & ~(size_t)255; };
    size_t o = 0;
    size_t rows_o = o;   o += al((size_t)E_ * 16 * 2);      // bf16 rows
    size_t eids_s_o = o; o += al((size_t)E_ * 4);
    size_t eids_r_o = o; o += al((size_t)E_ * 4);
    size_t off_s_o = o;  o += al((size_t)(N_ + 1) * 4);
    size_t off_r_o = o;  o += al((size_t)(N_ + 1) * 4);
    size_t deg_s_o = o;  o += al((size_t)N_ * 4);           // reused as cursors
    size_t deg_r_o = o;  o += al((size_t)N_ * 4);
    size_t bs_s_o = o;   o += al(1024 * 4);
    size_t bs_r_o = o;   o += al(1024 * 4);
    size_t sent_o = o;   o += al((size_t)N_ * 16 * 4);
    size_t recv_o = o;   o += al((size_t)N_ * 16 * 4);
    size_t nt_o = o;     o += al((size_t)N_ * 16 * 4);
    size_t need = o;

    if (ws_size >= need) {
        char* W = (char*)d_ws;
        unsigned short* rows = (unsigned short*)(W + rows_o);
        int* eids_s = (int*)(W + eids_s_o);
        int* eids_r = (int*)(W + eids_r_o);
        int* off_s = (int*)(W + off_s_o);
        int* off_r = (int*)(W + off_r_o);
        int* deg_s = (int*)(W + deg_s_o);  // then cursor
        int* deg_r = (int*)(W + deg_r_o);
        int* bs_s = (int*)(W + bs_s_o);
        int* bs_r = (int*)(W + bs_r_o);
        float* sent = (float*)(W + sent_o);
        float* recv = (float*)(W + recv_o);
        float* nodes_t = (float*)(W + nt_o);

        // CSR build
        hipMemsetAsync(deg_s, 0, (size_t)N_ * 4, stream);
        hipMemsetAsync(deg_r, 0, (size_t)N_ * 4, stream);
        hist_kernel<<<gridE, BLK, 0, stream>>>(senders, receivers, deg_s, deg_r, E_);
        int nblk = (N_ + 1023) / 1024;
        scan_local_kernel<<<nblk, 256, 0, stream>>>(deg_s, off_s, bs_s, N_);
        scan_local_kernel<<<nblk, 256, 0, stream>>>(deg_r, off_r, bs_r, N_);
        scan_tops_kernel<<<1, 256, 0, stream>>>(bs_s, nblk);
        scan_tops_kernel<<<1, 256, 0, stream>>>(bs_r, nblk);
        scan_add_kernel<<<nblk, 256, 0, stream>>>(off_s, bs_s, N_, E_);
        scan_add_kernel<<<nblk, 256, 0, stream>>>(off_r, bs_r, N_, E_);
        copy2_kernel<<<gridN, BLK, 0, stream>>>(off_s, deg_s, off_r, deg_r, N_);
        fill_kernel<<<gridE, BLK, 0, stream>>>(senders, receivers, deg_s, deg_r,
                                               eids_s, eids_r, E_);
        // edges -> bf16 rows
        transpose_in_kernel<<<gridE, BLK, 0, stream>>>(edges0, rows, E_);

        const int gridA = (N_ * 16 + BLK - 1) / BLK;
        const float* ncur = nodes0;
        for (int r = 0; r < 5; ++r) {
            aggregate_kernel<<<gridA, BLK, 0, stream>>>(rows, off_s, eids_s, sent, N_);
            aggregate_kernel<<<gridA, BLK, 0, stream>>>(rows, off_r, eids_r, recv, N_);
            node_mlp_kernel<<<gridN, BLK, 0, stream>>>(ncur, sent, recv,
                                                       nW1, nb1, nW2, nb2,
                                                       out_nodes, nodes_t, N_);
            if (r < 4) {
                edge_mlp_rows_kernel<0><<<gridE, BLK, 0, stream>>>(rows, nodes_t,
                                                                   senders, receivers,
                                                                   eW1, eb1, eW2, eb2,
                                                                   nullptr, E_);
            } else {
                edge_mlp_rows_kernel<1><<<gridE, BLK, 0, stream>>>(rows, nodes_t,
                                                                   senders, receivers,
                                                                   eW1, eb1, eW2, eb2,
                                                                   out_edges, E_);
            }
            ncur = out_nodes;
        }
    } else {
        // -------- fallback: previous (passing) atomic path --------
        float* wsf = (float*)d_ws;
        float* SR0 = wsf;
        float* S0 = SR0;
        float* R0 = SR0 + (size_t)16 * N_;
        float* SR1 = wsf + (size_t)32 * N_;
        float* S1 = SR1;
        float* R1 = SR1 + (size_t)16 * N_;
        float* nodes_t = wsf + (size_t)64 * N_;

        hipMemsetAsync(SR0, 0, sizeof(float) * (size_t)32 * N_, stream);
        scatter_kernel<<<gridE, BLK, 0, stream>>>(edges0, senders, receivers, S0, R0, E_);

        const float* ncur = nodes0;
        const float* ecur = edges0;
        for (int r = 0; r < 5; ++r) {
            float* Scur = (r & 1) ? S1 : S0;
            float* Rcur = (r & 1) ? R1 : R0;
            float* Snxt = (r & 1) ? S0 : S1;
            float* Rnxt = (r & 1) ? R0 : R1;

            node_mlp_kernel<<<gridN, BLK, 0, stream>>>(ncur, Scur, Rcur,
                                                       nW1, nb1, nW2, nb2,
                                                       out_nodes, nodes_t, N_);
            if (r < 4) {
                hipMemsetAsync((r & 1) ? SR0 : SR1, 0, sizeof(float) * (size_t)32 * N_, stream);
                edge_mlp_kernel<1><<<gridE, BLK, 0, stream>>>(ecur, nodes_t, senders, receivers,
                                                              eW1, eb1, eW2, eb2,
                                                              out_edges, Snxt, Rnxt, E_);
            } else {
                edge_mlp_kernel<0><<<gridE, BLK, 0, stream>>>(ecur, nodes_t, senders, receivers,
                                                              eW1, eb1, eW2, eb2,
                                                              out_edges, nullptr, nullptr, E_);
            }
            ncur = out_nodes;
            ecur = out_edges;
        }
    }
}